// Round 3
// baseline (50.743 us; speedup 1.0000x reference)
//
#include <hip/hip_runtime.h>

// out[k,i,l] = sum_{j<l} w[i,j]*x[k,j] + bias[i]
// B=128, N_h=512, size_in=1024.
// One 64-lane wave per output row (k,i). Lane owns 4 consecutive floats per
// 256-element chunk -> float4 coalesced loads/stores.
// R3 = R2 with native clang vector type for nontemporal stores
// (__builtin_nontemporal_store rejects HIP_vector_type float4).

#define SIZE_IN 1024
#define N_H 512

typedef float f32x4 __attribute__((ext_vector_type(4)));

__global__ __launch_bounds__(256) void nade_kernel(
    const float* __restrict__ x,     // [B, SIZE_IN]
    const float* __restrict__ w,     // [N_H, SIZE_IN]
    const float* __restrict__ bias,  // [N_H]
    float* __restrict__ out)         // [B, N_H, SIZE_IN]
{
    const int lane = threadIdx.x & 63;
    const int wave = threadIdx.x >> 6;
    const int row  = blockIdx.x * 4 + wave;   // row = k*N_H + i
    const int k = row >> 9;                   // row / N_H
    const int i = row & (N_H - 1);            // row % N_H

    const float* xr = x + (size_t)k * SIZE_IN;
    const float* wr = w + (size_t)i * SIZE_IN;
    float* outr = out + (size_t)row * SIZE_IN;
    const float b = bias[i];

    // ---- load all 4 chunks (static indices only; stays in registers) ----
    f32x4 xv[4], wv[4];
#pragma unroll
    for (int c = 0; c < 4; ++c) {
        const int j0 = c * 256 + lane * 4;
        xv[c] = *reinterpret_cast<const f32x4*>(xr + j0);
        wv[c] = *reinterpret_cast<const f32x4*>(wr + j0);
    }

    // ---- in-lane inclusive prefixes of the 4 products, per chunk ----
    float p0[4], p1[4], p2[4], p3[4], s[4];
#pragma unroll
    for (int c = 0; c < 4; ++c) {
        p0[c] = xv[c].x * wv[c].x;
        p1[c] = p0[c] + xv[c].y * wv[c].y;
        p2[c] = p1[c] + xv[c].z * wv[c].z;
        p3[c] = p2[c] + xv[c].w * wv[c].w;
        s[c]  = p3[c];
    }

    // ---- 4 independent wave-wide inclusive scans, interleaved (ILP) ----
#pragma unroll
    for (int d = 1; d < 64; d <<= 1) {
#pragma unroll
        for (int c = 0; c < 4; ++c) {
            const float n = __shfl_up(s[c], d, 64);
            if (lane >= d) s[c] += n;
        }
    }

    // ---- chunk totals -> per-chunk carries (3 shuffles, short chain) ----
    const float tot0 = __shfl(s[0], 63, 64);
    const float tot1 = __shfl(s[1], 63, 64);
    const float tot2 = __shfl(s[2], 63, 64);
    float carry[4];
    carry[0] = b;
    carry[1] = b + tot0;
    carry[2] = carry[1] + tot1;
    carry[3] = carry[2] + tot2;

    // ---- stores: exclusive prefix + bias, nontemporal float4 ----
#pragma unroll
    for (int c = 0; c < 4; ++c) {
        const int j0 = c * 256 + lane * 4;
        const float excl = carry[c] + (s[c] - p3[c]);
        f32x4 ov;
        ov.x = excl;
        ov.y = excl + p0[c];
        ov.z = excl + p1[c];
        ov.w = excl + p2[c];
        __builtin_nontemporal_store(ov, reinterpret_cast<f32x4*>(outr + j0));
    }
}

extern "C" void kernel_launch(void* const* d_in, const int* in_sizes, int n_in,
                              void* d_out, int out_size, void* d_ws, size_t ws_size,
                              hipStream_t stream) {
    const float* x    = (const float*)d_in[0];
    const float* w    = (const float*)d_in[1];
    const float* bias = (const float*)d_in[2];
    float* out = (float*)d_out;

    const int B = in_sizes[0] / SIZE_IN;      // 128
    const int rows = B * N_H;                  // 65536
    const int blocks = rows / 4;               // 4 waves/block, 1 row/wave

    nade_kernel<<<blocks, 256, 0, stream>>>(x, w, bias, out);
}

// Round 5
// 45.120 us; speedup vs baseline: 1.1246x; 1.1246x over previous
//
#include <hip/hip_runtime.h>

// out[k,i,l] = sum_{j<l} w[i,j]*x[k,j] + bias[i]
// B=128, N_h=512, size_in=1024.
// One 64-lane wave per output row (k,i). Lane owns 4 consecutive floats per
// 256-element chunk -> float4 coalesced loads/stores (1KB/instr).
// R5 = R4 with DPP ctrl/mask as TEMPLATE parameters (the builtin requires
// integer constant expressions; plain function args don't qualify).

#define SIZE_IN 1024
#define N_H 512

typedef float f32x4 __attribute__((ext_vector_type(4)));

template <int CTRL, int ROW_MASK>
__device__ __forceinline__ float dpp_add(float x) {
    // x += DPP-moved(x); masked-off / out-of-bounds lanes contribute 0.
    int moved = __builtin_amdgcn_update_dpp(0, __float_as_int(x), CTRL,
                                            ROW_MASK, 0xf, true);
    return x + __int_as_float(moved);
}

__device__ __forceinline__ float wave_incl_scan(float x) {
    x = dpp_add<0x111, 0xf>(x);  // row_shr:1
    x = dpp_add<0x112, 0xf>(x);  // row_shr:2
    x = dpp_add<0x114, 0xf>(x);  // row_shr:4
    x = dpp_add<0x118, 0xf>(x);  // row_shr:8
    x = dpp_add<0x142, 0xa>(x);  // row_bcast:15 -> rows 1,3
    x = dpp_add<0x143, 0xc>(x);  // row_bcast:31 -> rows 2,3
    return x;
}

__global__ __launch_bounds__(256) void nade_kernel(
    const float* __restrict__ x,     // [B, SIZE_IN]
    const float* __restrict__ w,     // [N_H, SIZE_IN]
    const float* __restrict__ bias,  // [N_H]
    float* __restrict__ out)         // [B, N_H, SIZE_IN]
{
    const int lane = threadIdx.x & 63;
    const int wave = threadIdx.x >> 6;
    const int row  = blockIdx.x * 4 + wave;   // row = k*N_H + i
    const int k = row >> 9;                   // row / N_H
    const int i = row & (N_H - 1);            // row % N_H

    const float* xr = x + (size_t)k * SIZE_IN;
    const float* wr = w + (size_t)i * SIZE_IN;
    float* outr = out + (size_t)row * SIZE_IN;

    float carry = bias[i];                    // bias folded into the carry
#pragma unroll
    for (int c = 0; c < 4; ++c) {
        const int j0 = c * 256 + lane * 4;
        const f32x4 xv = *reinterpret_cast<const f32x4*>(xr + j0);
        const f32x4 wv = *reinterpret_cast<const f32x4*>(wr + j0);
        // in-lane inclusive prefix of the 4 products
        const float p0 = xv.x * wv.x;
        const float p1 = p0 + xv.y * wv.y;
        const float p2 = p1 + xv.z * wv.z;
        const float p3 = p2 + xv.w * wv.w;
        // wave-wide inclusive scan of per-lane sums (6 DPP adds, no DS)
        const float s = wave_incl_scan(p3);
        const float excl = carry + (s - p3);  // exclusive prefix at lane start
        f32x4 ov;
        ov.x = excl;
        ov.y = excl + p0;
        ov.z = excl + p1;
        ov.w = excl + p2;
        *reinterpret_cast<f32x4*>(outr + j0) = ov;
        // chunk total = lane 63's inclusive value (wave-uniform via readlane)
        carry += __int_as_float(__builtin_amdgcn_readlane(__float_as_int(s), 63));
    }
}

extern "C" void kernel_launch(void* const* d_in, const int* in_sizes, int n_in,
                              void* d_out, int out_size, void* d_ws, size_t ws_size,
                              hipStream_t stream) {
    const float* x    = (const float*)d_in[0];
    const float* w    = (const float*)d_in[1];
    const float* bias = (const float*)d_in[2];
    float* out = (float*)d_out;

    const int B = in_sizes[0] / SIZE_IN;      // 128
    const int rows = B * N_H;                  // 65536
    const int blocks = rows / 4;               // 4 waves/block, 1 row/wave

    nade_kernel<<<blocks, 256, 0, stream>>>(x, w, bias, out);
}